// Round 1
// baseline (464.885 us; speedup 1.0000x reference)
//
#include <hip/hip_runtime.h>

typedef unsigned short u16;
typedef unsigned int u32;
typedef __attribute__((ext_vector_type(8))) short bf16x8;
typedef __attribute__((ext_vector_type(4))) float f32x4;

// dims
#define BATCH 128
#define NQL   384
#define NKL   384
#define NHEAD 8
#define HD    32      // key/value dim per head
#define ADIM  256

__device__ __forceinline__ u16 f2bf(float f) {
    union { float f; u32 u; } v; v.f = f;
    u32 r = v.u + 0x7fffu + ((v.u >> 16) & 1u);
    return (u16)(r >> 16);
}
__device__ __forceinline__ float bf2f(u16 u) {
    union { u32 u; float f; } v; v.u = ((u32)u) << 16;
    return v.f;
}
__device__ __forceinline__ u32 pk(float a, float b) {
    return (u32)f2bf(a) | ((u32)f2bf(b) << 16);
}

// ---------------------------------------------------------------------------
// Kernel 1: convert+transpose 5 weight matrices fp32 [K=256][N=256] -> bf16 [N][K]
// grid (16, 5) x 256 threads
// ---------------------------------------------------------------------------
__global__ __launch_bounds__(256) void prep_w_kernel(
    const float* __restrict__ qw, const float* __restrict__ kw,
    const float* __restrict__ vw, const float* __restrict__ gw,
    const float* __restrict__ ow, u16* __restrict__ wt)
{
    const float* src;
    switch (blockIdx.y) {
        case 0: src = qw; break;
        case 1: src = kw; break;
        case 2: src = vw; break;
        case 3: src = gw; break;
        default: src = ow; break;
    }
    u16* dst = wt + (size_t)blockIdx.y * 65536;
    int t = threadIdx.x;            // k index, coalesced-ish writes
    int n0 = blockIdx.x * 16;
    for (int i = 0; i < 16; i++) {
        int n = n0 + i;
        dst[n * 256 + t] = f2bf(src[t * 256 + n]);
    }
}

// ---------------------------------------------------------------------------
// Kernel 2: fused 4-way projection GEMM.
// C[M=49152, N=256] = A[M,256] x W[256,256]  (bf16 MFMA, fp32 acc)
// z=0: q = (q_data x query_w)*scale ; z=1: k ; z=2: v ; z=3: gate=sigmoid(+gb)
// grid (384, 2, 4) x 256 threads; block tile 128x128, wave tile 64x64
// ---------------------------------------------------------------------------
__global__ __launch_bounds__(256) void proj4_kernel(
    const float* __restrict__ qd, const float* __restrict__ md,
    const u16* __restrict__ wt, const float* __restrict__ gb,
    u16* __restrict__ q_o, u16* __restrict__ k_o,
    u16* __restrict__ v_o, u16* __restrict__ g_o)
{
    const int z = blockIdx.z;
    const float* A = (z == 0 || z == 3) ? qd : md;
    const u16* W = wt + (size_t)z * 65536;      // [n][k] bf16
    u16* O = (z == 0) ? q_o : (z == 1) ? k_o : (z == 2) ? v_o : g_o;

    const int bm = blockIdx.x * 128, bn = blockIdx.y * 128;
    const int tid = threadIdx.x;
    const int lane = tid & 63, wave = tid >> 6;
    const int col = lane & 15, quad = lane >> 4;
    const int mw = (wave & 1) * 64, nw = (wave >> 1) * 64;

    __shared__ u16 As[128][32];   // [m][k] rows 64B -> conflict-free b128 frag reads
    __shared__ u16 Ws[128][32];   // [n][k]

    f32x4 acc[4][4];
#pragma unroll
    for (int i = 0; i < 4; i++)
#pragma unroll
        for (int j = 0; j < 4; j++) acc[i][j] = (f32x4){0.f, 0.f, 0.f, 0.f};

    const int arow = tid >> 1, acb = (tid & 1) * 16;
    const float* asrc = A + (size_t)(bm + arow) * 256 + acb;
    const u16*   wsrc = W + (size_t)(bn + arow) * 256 + acb;

    for (int k0 = 0; k0 < 256; k0 += 32) {
        __syncthreads();
        {
            float4 f0 = *(const float4*)(asrc + k0 + 0);
            float4 f1 = *(const float4*)(asrc + k0 + 4);
            float4 f2 = *(const float4*)(asrc + k0 + 8);
            float4 f3 = *(const float4*)(asrc + k0 + 12);
            uint4 u0 = make_uint4(pk(f0.x, f0.y), pk(f0.z, f0.w), pk(f1.x, f1.y), pk(f1.z, f1.w));
            uint4 u1 = make_uint4(pk(f2.x, f2.y), pk(f2.z, f2.w), pk(f3.x, f3.y), pk(f3.z, f3.w));
            *(uint4*)&As[arow][acb + 0] = u0;
            *(uint4*)&As[arow][acb + 8] = u1;
            *(uint4*)&Ws[arow][acb + 0] = *(const uint4*)(wsrc + k0 + 0);
            *(uint4*)&Ws[arow][acb + 8] = *(const uint4*)(wsrc + k0 + 8);
        }
        __syncthreads();
        bf16x8 bv[4];
#pragma unroll
        for (int nt = 0; nt < 4; nt++)
            bv[nt] = *(const bf16x8*)&Ws[nw + nt * 16 + col][quad * 8];
#pragma unroll
        for (int mt = 0; mt < 4; mt++) {
            bf16x8 av = *(const bf16x8*)&As[mw + mt * 16 + col][quad * 8];
#pragma unroll
            for (int nt = 0; nt < 4; nt++)
                acc[mt][nt] = __builtin_amdgcn_mfma_f32_16x16x32_bf16(av, bv[nt], acc[mt][nt], 0, 0, 0);
        }
    }

    // epilogue: C layout col=lane&15, row=quad*4+r
#pragma unroll
    for (int nt = 0; nt < 4; nt++) {
        int gn = bn + nw + nt * 16 + col;
        float gbv = (z == 3) ? gb[gn] : 0.f;
#pragma unroll
        for (int mt = 0; mt < 4; mt++) {
#pragma unroll
            for (int r = 0; r < 4; r++) {
                int gm = bm + mw + mt * 16 + quad * 4 + r;
                float v = acc[mt][nt][r];
                if (z == 0) v *= 0.17677669529663689f;   // 1/sqrt(32)
                if (z == 3) v = 1.f / (1.f + __expf(-(v + gbv)));
                O[(size_t)gm * 256 + gn] = f2bf(v);
            }
        }
    }
}

// ---------------------------------------------------------------------------
// Kernel 3: attention per (b, h, 64 q rows). 4 waves x 16 q rows each.
// S = Q K^T (+bias +nb), rowwise softmax (quad-shuffle), O = P V, gate, store.
// grid (6, 8, 128) x 256 threads
// ---------------------------------------------------------------------------
__global__ __launch_bounds__(256) void attn_kernel(
    const u16* __restrict__ q_ws, const u16* __restrict__ k_ws,
    const u16* __restrict__ v_ws, const u16* __restrict__ g_ws,
    const float* __restrict__ bias, const float* __restrict__ nb,
    u16* __restrict__ wa_ws)
{
    const int b = blockIdx.z, h = blockIdx.y;
    const int tid = threadIdx.x;
    const int lane = tid & 63, wave = tid >> 6;
    const int col = lane & 15, quad = lane >> 4;
    const int q0 = blockIdx.x * 64 + wave * 16;

    __shared__ u16 Ks[384][32];      // [kv][c]   rows 64B
    __shared__ u16 Vt[32][392];      // [c][kv]   pad +8 breaks bank conflicts
    __shared__ u16 Ps[4][16][72];    // per-wave P chunk [qrow][64 cols + pad 8]

    // stage K (flat copy) and V (transposed)
    const u16* kg = k_ws + ((size_t)b * 384) * 256 + h * 32;
    const u16* vg = v_ws + ((size_t)b * 384) * 256 + h * 32;
    for (int f = tid * 8; f < 384 * 32; f += 256 * 8) {
        int kr = f >> 5, c = f & 31;
        *(uint4*)&Ks[kr][c] = *(const uint4*)&kg[kr * 256 + c];
    }
    for (int f = tid * 8; f < 384 * 32; f += 256 * 8) {
        int kv = f >> 5, c = f & 31;
        u16 tmp[8];
        *(uint4*)tmp = *(const uint4*)&vg[kv * 256 + c];
#pragma unroll
        for (int j = 0; j < 8; j++) Vt[c + j][kv] = tmp[j];
    }
    __syncthreads();

    // Q fragment (A-operand): m=lane&15 -> q row, k=quad*8+j -> c
    const u16* qg = q_ws + ((size_t)(b * 384 + q0 + col)) * 256 + h * 32 + quad * 8;
    bf16x8 qf = *(const bf16x8*)qg;

    // S = Q K^T : 24 tiles of 16x16, one MFMA each (K=32 = full head dim)
    float S[24][4];
#pragma unroll
    for (int t = 0; t < 24; t++) {
        bf16x8 kf = *(const bf16x8*)&Ks[t * 16 + col][quad * 8];
        f32x4 a = (f32x4){0.f, 0.f, 0.f, 0.f};
        a = __builtin_amdgcn_mfma_f32_16x16x32_bf16(qf, kf, a, 0, 0, 0);
        S[t][0] = a[0]; S[t][1] = a[1]; S[t][2] = a[2]; S[t][3] = a[3];
    }

    // add bias + nonbatched bias (C layout: row=quad*4+r, col=t*16+col)
    const float* bp  = bias + ((size_t)b * 384 + q0 + quad * 4) * 384 + col;
    const float* nbp = nb + (size_t)(q0 + quad * 4) * 384 + col;
#pragma unroll
    for (int r = 0; r < 4; r++) {
#pragma unroll
        for (int t = 0; t < 24; t++)
            S[t][r] += bp[r * 384 + t * 16] + nbp[r * 384 + t * 16];
    }

    // softmax over 384 cols: in-lane over 24 tiles, then across 16 lanes of quad
#pragma unroll
    for (int r = 0; r < 4; r++) {
        float m = S[0][r];
#pragma unroll
        for (int t = 1; t < 24; t++) m = fmaxf(m, S[t][r]);
#pragma unroll
        for (int o = 1; o < 16; o <<= 1) m = fmaxf(m, __shfl_xor(m, o));
        float s = 0.f;
#pragma unroll
        for (int t = 0; t < 24; t++) { float p = __expf(S[t][r] - m); S[t][r] = p; s += p; }
#pragma unroll
        for (int o = 1; o < 16; o <<= 1) s += __shfl_xor(s, o);
        float inv = 1.f / s;
#pragma unroll
        for (int t = 0; t < 24; t++) S[t][r] *= inv;
    }

    // O = P V : P goes through LDS to convert C-layout -> A-layout (64-col chunks)
    f32x4 o0 = (f32x4){0.f, 0.f, 0.f, 0.f};
    f32x4 o1 = (f32x4){0.f, 0.f, 0.f, 0.f};
    for (int g = 0; g < 6; g++) {
#pragma unroll
        for (int tt = 0; tt < 4; tt++) {
            int t = g * 4 + tt;
#pragma unroll
            for (int r = 0; r < 4; r++)
                Ps[wave][quad * 4 + r][tt * 16 + col] = f2bf(S[t][r]);
        }
        asm volatile("s_waitcnt lgkmcnt(0)" ::: "memory");
        bf16x8 a0 = *(const bf16x8*)&Ps[wave][col][quad * 8];
        bf16x8 a1 = *(const bf16x8*)&Ps[wave][col][32 + quad * 8];
        bf16x8 b00 = *(const bf16x8*)&Vt[col][g * 64 + quad * 8];
        bf16x8 b01 = *(const bf16x8*)&Vt[col][g * 64 + 32 + quad * 8];
        bf16x8 b10 = *(const bf16x8*)&Vt[16 + col][g * 64 + quad * 8];
        bf16x8 b11 = *(const bf16x8*)&Vt[16 + col][g * 64 + 32 + quad * 8];
        o0 = __builtin_amdgcn_mfma_f32_16x16x32_bf16(a0, b00, o0, 0, 0, 0);
        o0 = __builtin_amdgcn_mfma_f32_16x16x32_bf16(a1, b01, o0, 0, 0, 0);
        o1 = __builtin_amdgcn_mfma_f32_16x16x32_bf16(a0, b10, o1, 0, 0, 0);
        o1 = __builtin_amdgcn_mfma_f32_16x16x32_bf16(a1, b11, o1, 0, 0, 0);
        asm volatile("s_waitcnt lgkmcnt(0)" ::: "memory");
    }

    // gate + store (wa layout [b,q,h*32+c] bf16)
    const size_t rowbase = (size_t)b * 384 + q0 + quad * 4;
#pragma unroll
    for (int r = 0; r < 4; r++) {
        size_t base = (rowbase + r) * 256 + h * 32;
        {
            size_t idx = base + col;
            wa_ws[idx] = f2bf(o0[r] * bf2f(g_ws[idx]));
        }
        {
            size_t idx = base + 16 + col;
            wa_ws[idx] = f2bf(o1[r] * bf2f(g_ws[idx]));
        }
    }
}

// ---------------------------------------------------------------------------
// Kernel 4: output projection. out[M,256] = wa[M,256] x output_w[256,256] + ob
// grid (384, 2) x 256 threads; fp32 output
// ---------------------------------------------------------------------------
__global__ __launch_bounds__(256) void outproj_kernel(
    const u16* __restrict__ wa, const u16* __restrict__ W,  // W: [n][k] bf16
    const float* __restrict__ ob, float* __restrict__ out)
{
    const int bm = blockIdx.x * 128, bn = blockIdx.y * 128;
    const int tid = threadIdx.x;
    const int lane = tid & 63, wave = tid >> 6;
    const int col = lane & 15, quad = lane >> 4;
    const int mw = (wave & 1) * 64, nw = (wave >> 1) * 64;

    __shared__ u16 As[128][32];
    __shared__ u16 Ws[128][32];

    f32x4 acc[4][4];
#pragma unroll
    for (int i = 0; i < 4; i++)
#pragma unroll
        for (int j = 0; j < 4; j++) acc[i][j] = (f32x4){0.f, 0.f, 0.f, 0.f};

    const int arow = tid >> 1, acb = (tid & 1) * 16;
    const u16* asrc = wa + (size_t)(bm + arow) * 256 + acb;
    const u16* wsrc = W + (size_t)(bn + arow) * 256 + acb;

    for (int k0 = 0; k0 < 256; k0 += 32) {
        __syncthreads();
        *(uint4*)&As[arow][acb + 0] = *(const uint4*)(asrc + k0 + 0);
        *(uint4*)&As[arow][acb + 8] = *(const uint4*)(asrc + k0 + 8);
        *(uint4*)&Ws[arow][acb + 0] = *(const uint4*)(wsrc + k0 + 0);
        *(uint4*)&Ws[arow][acb + 8] = *(const uint4*)(wsrc + k0 + 8);
        __syncthreads();
        bf16x8 bv[4];
#pragma unroll
        for (int nt = 0; nt < 4; nt++)
            bv[nt] = *(const bf16x8*)&Ws[nw + nt * 16 + col][quad * 8];
#pragma unroll
        for (int mt = 0; mt < 4; mt++) {
            bf16x8 av = *(const bf16x8*)&As[mw + mt * 16 + col][quad * 8];
#pragma unroll
            for (int nt = 0; nt < 4; nt++)
                acc[mt][nt] = __builtin_amdgcn_mfma_f32_16x16x32_bf16(av, bv[nt], acc[mt][nt], 0, 0, 0);
        }
    }

#pragma unroll
    for (int nt = 0; nt < 4; nt++) {
        int gn = bn + nw + nt * 16 + col;
        float obv = ob[gn];
#pragma unroll
        for (int mt = 0; mt < 4; mt++) {
#pragma unroll
            for (int r = 0; r < 4; r++) {
                int gm = bm + mw + mt * 16 + quad * 4 + r;
                out[(size_t)gm * 256 + gn] = acc[mt][nt][r] + obv;
            }
        }
    }
}

// ---------------------------------------------------------------------------
extern "C" void kernel_launch(void* const* d_in, const int* in_sizes, int n_in,
                              void* d_out, int out_size, void* d_ws, size_t ws_size,
                              hipStream_t stream)
{
    const float* q_data = (const float*)d_in[0];
    const float* m_data = (const float*)d_in[1];
    const float* bias   = (const float*)d_in[2];
    const float* nb     = (const float*)d_in[3];
    const float* qw     = (const float*)d_in[4];
    const float* kw     = (const float*)d_in[5];
    const float* vw     = (const float*)d_in[6];
    const float* gw     = (const float*)d_in[7];
    const float* gb     = (const float*)d_in[8];
    const float* ow     = (const float*)d_in[9];
    const float* ob     = (const float*)d_in[10];
    float* out = (float*)d_out;

    char* ws = (char*)d_ws;
    u16* wt = (u16*)ws;                               // 5 x 64K bf16 = 640 KB
    const size_t PROJ = (size_t)BATCH * NQL * 256;    // 12,582,912 elems
    u16* q_ws  = (u16*)(ws + (1 << 20));
    u16* k_ws  = q_ws + PROJ;
    u16* v_ws  = k_ws + PROJ;
    u16* g_ws  = v_ws + PROJ;
    u16* wa_ws = g_ws + PROJ;
    // total ws use: 1 MB + 5*25.17 MB ≈ 127 MB

    prep_w_kernel<<<dim3(16, 5), 256, 0, stream>>>(qw, kw, vw, gw, ow, wt);
    proj4_kernel<<<dim3(384, 2, 4), 256, 0, stream>>>(q_data, m_data, wt, gb,
                                                      q_ws, k_ws, v_ws, g_ws);
    attn_kernel<<<dim3(6, 8, 128), 256, 0, stream>>>(q_ws, k_ws, v_ws, g_ws,
                                                     bias, nb, wa_ws);
    outproj_kernel<<<dim3(384, 2), 256, 0, stream>>>(wa_ws, wt + 4 * 65536, ob, out);
}

// Round 2
// 445.452 us; speedup vs baseline: 1.0436x; 1.0436x over previous
//
#include <hip/hip_runtime.h>

typedef unsigned short u16;
typedef unsigned int u32;
typedef __attribute__((ext_vector_type(8))) short bf16x8;
typedef __attribute__((ext_vector_type(4))) float f32x4;

#define BATCH 128
#define NQL   384
#define NKL   384
#define NHEAD 8
#define HD    32
#define ADIM  256
#define QSCALE 0.17677669529663689f   // 1/sqrt(32)

__device__ __forceinline__ u16 f2bf(float f) {
    union { float f; u32 u; } v; v.f = f;
    u32 r = v.u + 0x7fffu + ((v.u >> 16) & 1u);
    return (u16)(r >> 16);
}
__device__ __forceinline__ float bf2f(u16 u) {
    union { u32 u; float f; } v; v.u = ((u32)u) << 16;
    return v.f;
}
__device__ __forceinline__ u32 pk(float a, float b) {
    return (u32)f2bf(a) | ((u32)f2bf(b) << 16);
}

// ---------------------------------------------------------------------------
// Kernel 1: convert+transpose 5 weight matrices fp32 [K=256][N=256] -> bf16 [N][K]
// ---------------------------------------------------------------------------
__global__ __launch_bounds__(256) void prep_w_kernel(
    const float* __restrict__ qw, const float* __restrict__ kw,
    const float* __restrict__ vw, const float* __restrict__ gw,
    const float* __restrict__ ow, u16* __restrict__ wt)
{
    const float* src;
    switch (blockIdx.y) {
        case 0: src = qw; break;
        case 1: src = kw; break;
        case 2: src = vw; break;
        case 3: src = gw; break;
        default: src = ow; break;
    }
    u16* dst = wt + (size_t)blockIdx.y * 65536;
    int t = threadIdx.x;
    int n0 = blockIdx.x * 16;
    for (int i = 0; i < 16; i++) {
        int n = n0 + i;
        dst[n * 256 + t] = f2bf(src[t * 256 + n]);
    }
}

// ---------------------------------------------------------------------------
// Kernel 2: merged projection GEMM. One A staging feeds TWO weight matrices.
// z=0: A=q_data -> q (scaled) + gate (sigmoid(+gb));  z=1: A=m_data -> k + v
// grid (384, 2, 2) x 256; block tile 128x128 per output, wave tile 64x64
// ---------------------------------------------------------------------------
__global__ __launch_bounds__(256) void proj2_kernel(
    const float* __restrict__ qd, const float* __restrict__ md,
    const u16* __restrict__ wt, const float* __restrict__ gb,
    u16* __restrict__ q_o, u16* __restrict__ k_o,
    u16* __restrict__ v_o, u16* __restrict__ g_o)
{
    const int z = blockIdx.z;
    const float* A = (z == 0) ? qd : md;
    const u16* W0 = wt + (size_t)(z == 0 ? 0 : 1) * 65536;   // query / key
    const u16* W1 = wt + (size_t)(z == 0 ? 3 : 2) * 65536;   // gating / value
    u16* O0 = (z == 0) ? q_o : k_o;
    u16* O1 = (z == 0) ? g_o : v_o;

    const int bm = blockIdx.x * 128, bn = blockIdx.y * 128;
    const int tid = threadIdx.x;
    const int lane = tid & 63, wave = tid >> 6;
    const int col = lane & 15, quad = lane >> 4;
    const int mw = (wave & 1) * 64, nw = (wave >> 1) * 64;

    __shared__ u16 As[128][32];
    __shared__ u16 Ws0[128][32];
    __shared__ u16 Ws1[128][32];

    f32x4 acc0[4][4], acc1[4][4];
#pragma unroll
    for (int i = 0; i < 4; i++)
#pragma unroll
        for (int j = 0; j < 4; j++) {
            acc0[i][j] = (f32x4){0.f, 0.f, 0.f, 0.f};
            acc1[i][j] = (f32x4){0.f, 0.f, 0.f, 0.f};
        }

    const int arow = tid >> 1, acb = (tid & 1) * 16;
    const float* asrc = A + (size_t)(bm + arow) * 256 + acb;
    const u16*   ws0  = W0 + (size_t)(bn + arow) * 256 + acb;
    const u16*   ws1  = W1 + (size_t)(bn + arow) * 256 + acb;

    for (int k0 = 0; k0 < 256; k0 += 32) {
        __syncthreads();
        {
            float4 f0 = *(const float4*)(asrc + k0 + 0);
            float4 f1 = *(const float4*)(asrc + k0 + 4);
            float4 f2 = *(const float4*)(asrc + k0 + 8);
            float4 f3 = *(const float4*)(asrc + k0 + 12);
            uint4 u0 = make_uint4(pk(f0.x, f0.y), pk(f0.z, f0.w), pk(f1.x, f1.y), pk(f1.z, f1.w));
            uint4 u1 = make_uint4(pk(f2.x, f2.y), pk(f2.z, f2.w), pk(f3.x, f3.y), pk(f3.z, f3.w));
            *(uint4*)&As[arow][acb + 0] = u0;
            *(uint4*)&As[arow][acb + 8] = u1;
            *(uint4*)&Ws0[arow][acb + 0] = *(const uint4*)(ws0 + k0 + 0);
            *(uint4*)&Ws0[arow][acb + 8] = *(const uint4*)(ws0 + k0 + 8);
            *(uint4*)&Ws1[arow][acb + 0] = *(const uint4*)(ws1 + k0 + 0);
            *(uint4*)&Ws1[arow][acb + 8] = *(const uint4*)(ws1 + k0 + 8);
        }
        __syncthreads();
        bf16x8 bv0[4], bv1[4];
#pragma unroll
        for (int nt = 0; nt < 4; nt++) {
            bv0[nt] = *(const bf16x8*)&Ws0[nw + nt * 16 + col][quad * 8];
            bv1[nt] = *(const bf16x8*)&Ws1[nw + nt * 16 + col][quad * 8];
        }
#pragma unroll
        for (int mt = 0; mt < 4; mt++) {
            bf16x8 av = *(const bf16x8*)&As[mw + mt * 16 + col][quad * 8];
#pragma unroll
            for (int nt = 0; nt < 4; nt++) {
                acc0[mt][nt] = __builtin_amdgcn_mfma_f32_16x16x32_bf16(av, bv0[nt], acc0[mt][nt], 0, 0, 0);
                acc1[mt][nt] = __builtin_amdgcn_mfma_f32_16x16x32_bf16(av, bv1[nt], acc1[mt][nt], 0, 0, 0);
            }
        }
    }

#pragma unroll
    for (int nt = 0; nt < 4; nt++) {
        int gn = bn + nw + nt * 16 + col;
        float gbv = (z == 0) ? gb[gn] : 0.f;
#pragma unroll
        for (int mt = 0; mt < 4; mt++) {
#pragma unroll
            for (int r = 0; r < 4; r++) {
                int gm = bm + mw + mt * 16 + quad * 4 + r;
                float v0 = acc0[mt][nt][r];
                float v1 = acc1[mt][nt][r];
                if (z == 0) {
                    v0 *= QSCALE;
                    v1 = 1.f / (1.f + __expf(-(v1 + gbv)));
                }
                O0[(size_t)gm * 256 + gn] = f2bf(v0);
                O1[(size_t)gm * 256 + gn] = f2bf(v1);
            }
        }
    }
}

// ---------------------------------------------------------------------------
// Kernel 3: attention. One block per (b,h), all 384 q rows; 4 waves x 6 q-tiles.
// K/V staged once. Bias+nb streamed through per-wave LDS chunk, used as MFMA
// C-operand (fp32 exact). Vt uses XOR granule swizzle (no pad, 64KB LDS fit).
// grid (1024) x 256
// ---------------------------------------------------------------------------
__global__ __launch_bounds__(256) void attn_kernel(
    const u16* __restrict__ q_ws, const u16* __restrict__ k_ws,
    const u16* __restrict__ v_ws, const u16* __restrict__ g_ws,
    const float* __restrict__ bias, const float* __restrict__ nb,
    u16* __restrict__ wa_ws)
{
    const int bi = blockIdx.x >> 3, h = blockIdx.x & 7;
    const int tid = threadIdx.x;
    const int lane = tid & 63, wave = tid >> 6;
    const int col = lane & 15, quad = lane >> 4;

    __shared__ u16 Ks[384][32];                  // 24576 B
    __shared__ u16 Vt[32 * 384];                 // 24576 B, [c][kv] xor-swizzled
    __shared__ __align__(16) char scratch[4][4096];  // per-wave: Bs f32[16][64] / Ps u16[16][72]
    float* Bs = (float*)scratch[wave];
    u16*   Ps = (u16*)scratch[wave];

    // stage K
    const u16* kg = k_ws + (size_t)bi * 384 * 256 + h * 32;
    const u16* vg = v_ws + (size_t)bi * 384 * 256 + h * 32;
    for (int f = tid * 8; f < 384 * 32; f += 256 * 8) {
        int kr = f >> 5, c = f & 31;
        *(uint4*)&Ks[kr][c] = *(const uint4*)&kg[kr * 256 + c];
    }
    // stage V transposed with 16B-granule XOR swizzle: elem (c,kv) at
    // c*384 + (((kv>>3) ^ (c&7))<<3) + (kv&7)
    for (int f = tid * 8; f < 384 * 32; f += 256 * 8) {
        int kv = f >> 5, c0 = f & 31;
        u16 tmp[8];
        *(uint4*)tmp = *(const uint4*)&vg[kv * 256 + c0];
        int kvg = kv >> 3, kvr = kv & 7;
#pragma unroll
        for (int j = 0; j < 8; j++) {
            int c = c0 + j;
            Vt[c * 384 + ((kvg ^ (c & 7)) << 3) + kvr] = tmp[j];
        }
    }
    __syncthreads();

    for (int qt = wave; qt < 24; qt += 4) {
        const int q0 = qt * 16;
        bf16x8 qf = *(const bf16x8*)(q_ws + ((size_t)(bi * 384 + q0 + col)) * 256 + h * 32 + quad * 8);

        const float* brow = bias + ((size_t)bi * 384 + q0) * 384;
        const float* nrow = nb + (size_t)q0 * 384;

        float S[24][4];
#pragma unroll
        for (int g = 0; g < 6; g++) {
            // stage bias chunk [16 q rows][64 kv cols] coalesced into Bs
#pragma unroll
            for (int i = 0; i < 4; i++) {
                int flat = lane + 64 * i;            // 0..255
                int row = flat >> 4, c4 = (flat & 15) << 2;
                float4 bv = *(const float4*)&brow[(size_t)row * 384 + g * 64 + c4];
                float4 nv = *(const float4*)&nrow[(size_t)row * 384 + g * 64 + c4];
                float4 sv = make_float4(bv.x + nv.x, bv.y + nv.y, bv.z + nv.z, bv.w + nv.w);
                *(float4*)&Bs[row * 64 + c4] = sv;
            }
            asm volatile("s_waitcnt lgkmcnt(0)" ::: "memory");
#pragma unroll
            for (int tt = 0; tt < 4; tt++) {
                int t = g * 4 + tt;
                f32x4 ci;
#pragma unroll
                for (int r = 0; r < 4; r++)
                    ci[r] = Bs[(quad * 4 + r) * 64 + tt * 16 + col];
                bf16x8 kf = *(const bf16x8*)&Ks[t * 16 + col][quad * 8];
                f32x4 a = __builtin_amdgcn_mfma_f32_16x16x32_bf16(qf, kf, ci, 0, 0, 0);
                S[t][0] = a[0]; S[t][1] = a[1]; S[t][2] = a[2]; S[t][3] = a[3];
            }
            asm volatile("s_waitcnt lgkmcnt(0)" ::: "memory");
        }

        // softmax over 384 cols: in-lane over 24 tiles + xor-shuffle over 16 lanes
#pragma unroll
        for (int r = 0; r < 4; r++) {
            float m = S[0][r];
#pragma unroll
            for (int t = 1; t < 24; t++) m = fmaxf(m, S[t][r]);
#pragma unroll
            for (int o = 1; o < 16; o <<= 1) m = fmaxf(m, __shfl_xor(m, o));
            float s = 0.f;
#pragma unroll
            for (int t = 0; t < 24; t++) { float p = __expf(S[t][r] - m); S[t][r] = p; s += p; }
#pragma unroll
            for (int o = 1; o < 16; o <<= 1) s += __shfl_xor(s, o);
            float inv = 1.f / s;
#pragma unroll
            for (int t = 0; t < 24; t++) S[t][r] *= inv;
        }

        // O = P V via per-wave Ps round trip (C->A layout), swizzled Vt frags
        f32x4 o0 = (f32x4){0.f, 0.f, 0.f, 0.f};
        f32x4 o1 = (f32x4){0.f, 0.f, 0.f, 0.f};
#pragma unroll
        for (int g = 0; g < 6; g++) {
#pragma unroll
            for (int tt = 0; tt < 4; tt++) {
                int t = g * 4 + tt;
#pragma unroll
                for (int r = 0; r < 4; r++)
                    Ps[(quad * 4 + r) * 72 + tt * 16 + col] = f2bf(S[t][r]);
            }
            asm volatile("s_waitcnt lgkmcnt(0)" ::: "memory");
            bf16x8 a0 = *(const bf16x8*)&Ps[col * 72 + quad * 8];
            bf16x8 a1 = *(const bf16x8*)&Ps[col * 72 + 32 + quad * 8];
            const int e = col & 7;
            const int gg0 = g * 8 + quad;        // granule of kv = g*64 + quad*8
            const int gg1 = gg0 + 4;             // +32 kv
            bf16x8 b00 = *(const bf16x8*)&Vt[col * 384 + ((gg0 ^ e) << 3)];
            bf16x8 b01 = *(const bf16x8*)&Vt[col * 384 + ((gg1 ^ e) << 3)];
            bf16x8 b10 = *(const bf16x8*)&Vt[(col + 16) * 384 + ((gg0 ^ e) << 3)];
            bf16x8 b11 = *(const bf16x8*)&Vt[(col + 16) * 384 + ((gg1 ^ e) << 3)];
            o0 = __builtin_amdgcn_mfma_f32_16x16x32_bf16(a0, b00, o0, 0, 0, 0);
            o0 = __builtin_amdgcn_mfma_f32_16x16x32_bf16(a1, b01, o0, 0, 0, 0);
            o1 = __builtin_amdgcn_mfma_f32_16x16x32_bf16(a0, b10, o1, 0, 0, 0);
            o1 = __builtin_amdgcn_mfma_f32_16x16x32_bf16(a1, b11, o1, 0, 0, 0);
            asm volatile("s_waitcnt lgkmcnt(0)" ::: "memory");
        }

        // gate + store
        const size_t rowbase = (size_t)bi * 384 + q0 + quad * 4;
#pragma unroll
        for (int r = 0; r < 4; r++) {
            size_t base = (rowbase + r) * 256 + h * 32;
            {
                size_t idx = base + col;
                wa_ws[idx] = f2bf(o0[r] * bf2f(g_ws[idx]));
            }
            {
                size_t idx = base + 16 + col;
                wa_ws[idx] = f2bf(o1[r] * bf2f(g_ws[idx]));
            }
        }
    }
}

// ---------------------------------------------------------------------------
// Kernel 4: output projection. out[M,256] = wa[M,256] x output_w[256,256] + ob
// ---------------------------------------------------------------------------
__global__ __launch_bounds__(256) void outproj_kernel(
    const u16* __restrict__ wa, const u16* __restrict__ W,
    const float* __restrict__ ob, float* __restrict__ out)
{
    const int bm = blockIdx.x * 128, bn = blockIdx.y * 128;
    const int tid = threadIdx.x;
    const int lane = tid & 63, wave = tid >> 6;
    const int col = lane & 15, quad = lane >> 4;
    const int mw = (wave & 1) * 64, nw = (wave >> 1) * 64;

    __shared__ u16 As[128][32];
    __shared__ u16 Ws[128][32];

    f32x4 acc[4][4];
#pragma unroll
    for (int i = 0; i < 4; i++)
#pragma unroll
        for (int j = 0; j < 4; j++) acc[i][j] = (f32x4){0.f, 0.f, 0.f, 0.f};

    const int arow = tid >> 1, acb = (tid & 1) * 16;
    const u16* asrc = wa + (size_t)(bm + arow) * 256 + acb;
    const u16* wsrc = W + (size_t)(bn + arow) * 256 + acb;

    for (int k0 = 0; k0 < 256; k0 += 32) {
        __syncthreads();
        *(uint4*)&As[arow][acb + 0] = *(const uint4*)(asrc + k0 + 0);
        *(uint4*)&As[arow][acb + 8] = *(const uint4*)(asrc + k0 + 8);
        *(uint4*)&Ws[arow][acb + 0] = *(const uint4*)(wsrc + k0 + 0);
        *(uint4*)&Ws[arow][acb + 8] = *(const uint4*)(wsrc + k0 + 8);
        __syncthreads();
        bf16x8 bv[4];
#pragma unroll
        for (int nt = 0; nt < 4; nt++)
            bv[nt] = *(const bf16x8*)&Ws[nw + nt * 16 + col][quad * 8];
#pragma unroll
        for (int mt = 0; mt < 4; mt++) {
            bf16x8 av = *(const bf16x8*)&As[mw + mt * 16 + col][quad * 8];
#pragma unroll
            for (int nt = 0; nt < 4; nt++)
                acc[mt][nt] = __builtin_amdgcn_mfma_f32_16x16x32_bf16(av, bv[nt], acc[mt][nt], 0, 0, 0);
        }
    }

#pragma unroll
    for (int nt = 0; nt < 4; nt++) {
        int gn = bn + nw + nt * 16 + col;
        float obv = ob[gn];
#pragma unroll
        for (int mt = 0; mt < 4; mt++) {
#pragma unroll
            for (int r = 0; r < 4; r++) {
                int gm = bm + mw + mt * 16 + quad * 4 + r;
                out[(size_t)gm * 256 + gn] = acc[mt][nt][r] + obv;
            }
        }
    }
}

// ---------------------------------------------------------------------------
extern "C" void kernel_launch(void* const* d_in, const int* in_sizes, int n_in,
                              void* d_out, int out_size, void* d_ws, size_t ws_size,
                              hipStream_t stream)
{
    const float* q_data = (const float*)d_in[0];
    const float* m_data = (const float*)d_in[1];
    const float* bias   = (const float*)d_in[2];
    const float* nb     = (const float*)d_in[3];
    const float* qw     = (const float*)d_in[4];
    const float* kw     = (const float*)d_in[5];
    const float* vw     = (const float*)d_in[6];
    const float* gw     = (const float*)d_in[7];
    const float* gb     = (const float*)d_in[8];
    const float* ow     = (const float*)d_in[9];
    const float* ob     = (const float*)d_in[10];
    float* out = (float*)d_out;

    char* ws = (char*)d_ws;
    u16* wt = (u16*)ws;                               // 5 x 64K bf16 = 640 KB
    const size_t PROJ = (size_t)BATCH * NQL * 256;    // 12,582,912 elems
    u16* q_ws  = (u16*)(ws + (1 << 20));
    u16* k_ws  = q_ws + PROJ;
    u16* v_ws  = k_ws + PROJ;
    u16* g_ws  = v_ws + PROJ;
    u16* wa_ws = g_ws + PROJ;

    prep_w_kernel<<<dim3(16, 5), 256, 0, stream>>>(qw, kw, vw, gw, ow, wt);
    proj2_kernel<<<dim3(384, 2, 2), 256, 0, stream>>>(q_data, m_data, wt, gb,
                                                      q_ws, k_ws, v_ws, g_ws);
    attn_kernel<<<dim3(1024), 256, 0, stream>>>(q_ws, k_ws, v_ws, g_ws,
                                                bias, nb, wa_ws);
    outproj_kernel<<<dim3(384, 2), 256, 0, stream>>>(wa_ws, wt + 4 * 65536, ob, out);
}